// Round 3
// baseline (63.569 us; speedup 1.0000x reference)
//
#include <hip/hip_runtime.h>

// Light-cone-reduced circuit: entangled cluster = 64 amps = ONE wavefront,
// lane bits [b5..b0] = [edge0, edge1, vert1, vert2(measured), anc1, anc2].
//
// Round-3: remove the LDS round-trip from the serial chain. Each lane builds
// one matrix row in registers; rows are broadcast via v_readlane (constant
// lane -> SGPR). No __shared__, no __syncthreads, no per-gate ds_read_b128.
// Per-gate row-select eliminated algebraically: M1=-conj(M2), M3=conj(M0)
// =>  na = A*amp + B*p  with A={m0x, m0y^sA}, B={m2x^sB, m2y}, where
// sA/sB are per-lane sign masks (bit set / bit clear) hoisted once.

struct cplx { float x, y; };
__device__ __forceinline__ cplx cmul(cplx a, cplx b){ return {a.x*b.x - a.y*b.y, a.x*b.y + a.y*b.x}; }

// op encoding: bit0 = kind (0=rot, 1=cnot); bits[4:1] = target bit;
// bits[8:5] = ctrl bit (15 = none); bits[12:9] = matrix index (rot only).
#define OPR(b,m,c) (unsigned short)(((m)<<9)|((c)<<5)|((b)<<1))
#define OPC(c,t)   (unsigned short)(((c)<<5)|((t)<<1)|1)
// matrices: 0 CRx-angle 1 CRy1 2 CRz 3 CRy2 4 S0e 5 S0n 6 S0a 7 S1a 8 S1n 9 S1x
#define PASS(eb,nb) \
  OPR(1,0,nb), OPR(1,1,eb), OPR(0,2,nb), OPR(0,3,eb), \
  OPR(eb,4,15), OPR(nb,5,15), OPR(1,6,15), \
  OPC(eb,nb), OPC(nb,1), OPC(1,eb), \
  OPR(1,7,15), OPR(nb,8,15), OPR(0,9,15), \
  OPC(1,nb), OPC(nb,0), OPC(0,1)

constexpr unsigned short OPS[32] = { PASS(5,3), PASS(4,2) };

__device__ __forceinline__ float rlane(float v, int l){
  return __int_as_float(__builtin_amdgcn_readlane(__float_as_int(v), l));
}
__device__ __forceinline__ float fxor(float a, unsigned m){
  return __uint_as_float(__float_as_uint(a) ^ m);
}

__global__ __launch_bounds__(64)
void qlightcone(const float* __restrict__ inf, const float* __restrict__ inits,
                const float* __restrict__ s0p, const float* __restrict__ s1p,
                float* __restrict__ out)
{
  const int lane = threadIdx.x;

  // ---- builder: every lane computes row ml = (lane<14 ? lane : 4) in regs.
  // Row r: {M0.x, M0.y, M2.x, M2.y} of M = Rx*Ry*Rz (M1=-conj(M2), M3=conj(M0)).
  // rows 0-9: gate matrices; rows 10-13: initial spinors (tx=0 path):
  //   spin(bit) = bit ? conj(M2) : M0.
  float bax, bay, bbx, bby;
  {
    const int ml = (lane < 14) ? lane : 4;
    float tx = 0.f, ty = 0.f, tz = 0.f;
    if (ml < 4){
      const float a = inits[ml];
      tx = (ml == 0) ? a : 0.f;
      ty = (ml & 1)  ? a : 0.f;   // ml==1 || ml==3
      tz = (ml == 2) ? a : 0.f;
    } else if (ml < 10){
      const float* pp = (ml < 7) ? s0p + 3*(ml - 4) : s1p + 3*(ml - 7);
      tz = pp[0]; ty = pp[1]; tx = pp[2];   // reference applies Rz, Ry, Rx
    } else {
      // spinors: rows 10..13 <-> lane bits b5,b4,b3,b2; (ty,tz) at inf[{0,2,18,20}]
      const int q = ml - 10;
      const int idx = q*2 + ((q >= 2) ? 14 : 0);
      ty = inf[idx]; tz = inf[idx + 1];
    }
    const float sx = __sinf(0.5f*tx), cx = __cosf(0.5f*tx);
    const float sy = __sinf(0.5f*ty), cy = __cosf(0.5f*ty);
    const float sz = __sinf(0.5f*tz), cz = __cosf(0.5f*tz);
    // M = Rx*Ry*Rz:  M0 = u*w, M2 = v*w
    const cplx u = { cx*cy, -sx*sy };
    const cplx v = { cx*sy, -sx*cy };
    const cplx w = { cz, -sz };
    const cplx a = cmul(u, w), b = cmul(v, w);
    bax = a.x; bay = a.y; bbx = b.x; bby = b.y;
  }

  // ---- lane-bit predicates + per-bit sign masks for the row-select identity
  bool bt[6]; unsigned mA[6], mB[6];
  #pragma unroll
  for (int k = 0; k < 6; ++k){
    bt[k] = (lane >> k) & 1;
    mA[k] = bt[k] ? 0x80000000u : 0u;   // flip sign when bit set   (A.y)
    mB[k] = mA[k] ^ 0x80000000u;        // flip sign when bit clear (B.x)
  }

  // ---- initial product state from spinor rows 10-13; anc b1,b0 = |0>
  cplx amp = {1.f, 0.f};
  #pragma unroll
  for (int q = 0; q < 4; ++q){
    const int r = 10 + q;
    const float m0x = rlane(bax, r), m0y = rlane(bay, r);
    const float m2x = rlane(bbx, r), m2y = rlane(bby, r);
    const bool bit = bt[5 - q];
    const cplx s = { bit ? m2x : m0x, bit ? -m2y : m0y };
    amp = cmul(amp, s);
  }
  if (lane & 3) amp = {0.f, 0.f};

  // ---- broadcast the 10 gate matrices into uniform scalars (SGPRs)
  float g0x[10], g0y[10], g2x[10], g2y[10];
  #pragma unroll
  for (int r = 0; r < 10; ++r){
    g0x[r] = rlane(bax, r); g0y[r] = rlane(bay, r);
    g2x[r] = rlane(bbx, r); g2y[r] = rlane(bby, r);
  }

  // ---- gate sequence, fully unrolled; every mask/index folds to an immediate
  #pragma unroll
  for (int i = 0; i < 32; ++i){
    const int op   = OPS[i];
    const int b    = (op >> 1) & 15;
    const int c    = (op >> 5) & 15;
    const cplx p   = { __shfl_xor(amp.x, 1 << b), __shfl_xor(amp.y, 1 << b) };
    const bool cok = (c == 15) || bt[c];
    if (op & 1){                       // CNOT: swap pair where ctrl set
      if (cok) amp = p;
    } else {                           // controlled/plain 2x2 rotation
      const int m = (op >> 9) & 15;
      // lane row: A = hi ? M3 : M0 = {m0x, m0y^mA[b]}
      //           B = hi ? M2 : M1 = {m2x^mB[b], m2y}
      const float Ax = g0x[m];
      const float Ay = fxor(g0y[m], mA[b]);
      const float Bx = fxor(g2x[m], mB[b]);
      const float By = g2y[m];
      cplx na;
      na.x = Ax*amp.x - Ay*amp.y + Bx*p.x - By*p.y;
      na.y = Ax*amp.y + Ay*amp.x + Bx*p.y + By*p.x;
      if (cok) amp = na;
    }
  }

  // ---- <Z> on measured bit b2
  float s = amp.x*amp.x + amp.y*amp.y;
  if (bt[2]) s = -s;
  #pragma unroll
  for (int off = 32; off > 0; off >>= 1) s += __shfl_down(s, off);
  if (lane == 0) out[0] = s;
}

extern "C" void kernel_launch(void* const* d_in, const int* in_sizes, int n_in,
                              void* d_out, int out_size, void* d_ws, size_t ws_size,
                              hipStream_t stream) {
  const float* inf   = (const float*)d_in[0];
  const float* inits = (const float*)d_in[1];
  const float* s0p   = (const float*)d_in[2];
  const float* s1p   = (const float*)d_in[3];
  // d_in[4] (update_params) provably cannot affect the output: unitary outside
  // the light cone (verified absmax 0.0 against the JAX reference).
  float* out = (float*)d_out;

  qlightcone<<<dim3(1), dim3(64), 0, stream>>>(inf, inits, s0p, s1p, out);
}

// Round 4
// 61.304 us; speedup vs baseline: 1.0369x; 1.0369x over previous
//
#include <hip/hip_runtime.h>

// Light-cone-reduced circuit: entangled cluster = 64 amps = ONE wavefront,
// lane bits [b5..b0] = [edge0, edge1, vert1, vert2(measured), anc1, anc2].
//
// Round-4: round-2 structure (LDS broadcast + full unroll, best measured) with
// the prologue's serial cold-miss chain fixed:
//  - BRANCH-FREE builder: per-lane (tz,ty,tx) addresses selected via cndmask,
//    three independent global_load_dword issued together -> all four input
//    buffers' cold HBM misses (post-poison) overlap in one vmcnt window.
//    (Previous 3-way divergent if/else serialized the misses.)
//  - The 10 gate matrices are hoisted from LDS into registers in one batch of
//    ds_read_b128 (constant offsets) before the gate chain.

struct cplx { float x, y; };
__device__ __forceinline__ cplx cmul(cplx a, cplx b){ return {a.x*b.x - a.y*b.y, a.x*b.y + a.y*b.x}; }

// op encoding: bit0 = kind (0=rot, 1=cnot); bits[4:1] = target bit;
// bits[8:5] = ctrl bit (15 = none); bits[12:9] = matrix index (rot only).
#define OPR(b,m,c) (unsigned short)(((m)<<9)|((c)<<5)|((b)<<1))
#define OPC(c,t)   (unsigned short)(((c)<<5)|((t)<<1)|1)
// matrices: 0 CRx-angle 1 CRy1 2 CRz 3 CRy2 4 S0e 5 S0n 6 S0a 7 S1a 8 S1n 9 S1x
#define PASS(eb,nb) \
  OPR(1,0,nb), OPR(1,1,eb), OPR(0,2,nb), OPR(0,3,eb), \
  OPR(eb,4,15), OPR(nb,5,15), OPR(1,6,15), \
  OPC(eb,nb), OPC(nb,1), OPC(1,eb), \
  OPR(1,7,15), OPR(nb,8,15), OPR(0,9,15), \
  OPC(1,nb), OPC(nb,0), OPC(0,1)

constexpr unsigned short OPS[32] = { PASS(5,3), PASS(4,2) };

__global__ __launch_bounds__(64)
void qlightcone(const float* __restrict__ inf, const float* __restrict__ inits,
                const float* __restrict__ s0p, const float* __restrict__ s1p,
                float* __restrict__ out)
{
  // Mlds[i] = {M0.x, M0.y, M2.x, M2.y}; M1 = -conj(M2), M3 = conj(M0).
  // rows 0-9: gate matrices; rows 10-13: initial spinors (tx=0 path):
  //   spin(bit) = bit ? conj(M2) : M0.
  __shared__ float4 Mlds[14];
  const int lane = threadIdx.x;

  {
    const int ml  = (lane < 14) ? lane : 4;
    const int cls = (ml < 4) ? 0 : ((ml < 10) ? 1 : 2);

    // strong-param base (valid clamped pointer for every lane)
    const int si = (ml < 4) ? 0 : (ml - 4);          // 0..5 (clamped)
    const float* sp = (si < 3) ? (s0p + 3*si) : (s1p + 3*(si - 3));
    // spinor offset into inf: rows 10..13 -> (ty,tz) at inf[{0,2,18,20}]
    const int q   = ml - 10;
    const int idx = q*2 + ((q >= 2) ? 14 : 0);

    // branch-free per-lane addresses; three loads issue together
    const float* aZ = (cls == 0) ? (inits + ml) : ((cls == 1) ? (sp + 0) : (inf + idx + 1));
    const float* aY = (cls == 0) ? (inits + ml) : ((cls == 1) ? (sp + 1) : (inf + idx));
    const float* aX = (cls == 0) ? (inits + ml) : ((cls == 1) ? (sp + 2) : inits);
    const float lz = *aZ;
    const float ly = *aY;
    const float lx = *aX;

    const float tz = (cls == 1 || cls == 2 || ml == 2) ? lz : 0.f;
    const float ty = (cls != 0 || (ml & 1))            ? ly : 0.f;
    const float tx = (cls == 1 || ml == 0)             ? lx : 0.f;

    const float sx = __sinf(0.5f*tx), cx = __cosf(0.5f*tx);
    const float sy = __sinf(0.5f*ty), cy = __cosf(0.5f*ty);
    const float sz = __sinf(0.5f*tz), cz = __cosf(0.5f*tz);
    // M = Rx*Ry*Rz:  M0 = u*w, M2 = v*w
    const cplx u = { cx*cy, -sx*sy };
    const cplx v = { cx*sy, -sx*cy };
    const cplx w = { cz, -sz };
    const cplx a = cmul(u, w), b = cmul(v, w);
    if (lane < 14) Mlds[lane] = make_float4(a.x, a.y, b.x, b.y);
  }
  __syncthreads();

  // ---- lane-bit predicates
  bool bt[6];
  #pragma unroll
  for (int k = 0; k < 6; ++k) bt[k] = (lane >> k) & 1;

  // ---- initial product state from spinor rows 10-13; anc b1,b0 = |0>
  cplx amp = {1.f, 0.f};
  #pragma unroll
  for (int qq = 0; qq < 4; ++qq){
    const float4 mm = Mlds[10 + qq];
    const cplx s = bt[5 - qq] ? cplx{mm.z, -mm.w} : cplx{mm.x, mm.y};
    amp = cmul(amp, s);
  }
  if (lane & 3) amp = {0.f, 0.f};

  // ---- batch-hoist the 10 gate matrices (ds_read_b128 at constant offsets,
  //      latencies overlapped; gate chain then touches registers only)
  float4 G[10];
  #pragma unroll
  for (int r = 0; r < 10; ++r) G[r] = Mlds[r];

  // ---- gate sequence, fully unrolled; every mask/index folds to an immediate
  #pragma unroll
  for (int i = 0; i < 32; ++i){
    const int op   = OPS[i];
    const int b    = (op >> 1) & 15;
    const int c    = (op >> 5) & 15;
    const cplx p   = { __shfl_xor(amp.x, 1 << b), __shfl_xor(amp.y, 1 << b) };
    const bool cok = (c == 15) || bt[c];
    if (op & 1){                       // CNOT: swap pair where ctrl set
      if (cok) amp = p;
    } else {                           // controlled/plain 2x2 rotation
      const int m = (op >> 9) & 15;
      const float4 mm = G[m];
      const bool hi = bt[b];
      const cplx lo_ = hi ? p : amp, hi_ = hi ? amp : p;
      // row of M for this lane: lo: (M0, M1=-conj(M2)); hi: (M2, M3=conj(M0))
      const cplx A = hi ? cplx{mm.z, mm.w}   : cplx{mm.x, mm.y};
      const cplx B = hi ? cplx{mm.x, -mm.y}  : cplx{-mm.z, mm.w};
      cplx na;
      na.x = A.x*lo_.x - A.y*lo_.y + B.x*hi_.x - B.y*hi_.y;
      na.y = A.x*lo_.y + A.y*lo_.x + B.x*hi_.y + B.y*hi_.x;
      if (cok) amp = na;
    }
  }

  // ---- <Z> on measured bit b2
  float s = amp.x*amp.x + amp.y*amp.y;
  if (bt[2]) s = -s;
  #pragma unroll
  for (int off = 32; off > 0; off >>= 1) s += __shfl_down(s, off);
  if (lane == 0) out[0] = s;
}

extern "C" void kernel_launch(void* const* d_in, const int* in_sizes, int n_in,
                              void* d_out, int out_size, void* d_ws, size_t ws_size,
                              hipStream_t stream) {
  const float* inf   = (const float*)d_in[0];
  const float* inits = (const float*)d_in[1];
  const float* s0p   = (const float*)d_in[2];
  const float* s1p   = (const float*)d_in[3];
  // d_in[4] (update_params) provably cannot affect the output: unitary outside
  // the light cone (verified absmax 0.0 against the JAX reference).
  float* out = (float*)d_out;

  qlightcone<<<dim3(1), dim3(64), 0, stream>>>(inf, inits, s0p, s1p, out);
}